// Round 6
// baseline (21171.434 us; speedup 1.0000x reference)
//
#include <hip/hip_runtime.h>
#include <math.h>

#define TT 4096
#define HH 1500
#define NB 250     // blocks; each owns 6 hidden units
#define NT 512     // 8 waves: 0..5 = matvec (wave u = unit u, all 4 gates),
                   //          6 = x-proj + poll, 7 = poll

typedef unsigned long long u64;

#define ALD8(p)   __hip_atomic_load((p), __ATOMIC_RELAXED, __HIP_MEMORY_SCOPE_AGENT)
#define ALD4(p)   __hip_atomic_load((p), __ATOMIC_RELAXED, __HIP_MEMORY_SCOPE_AGENT)
#define AST4(p,v) __hip_atomic_store((p), (v), __ATOMIC_RELAXED, __HIP_MEMORY_SCOPE_AGENT)

__device__ __forceinline__ float fast_sigmoid(float z) {
  return 1.0f / (1.0f + __expf(-z));
}
__device__ __forceinline__ float fast_tanh(float z) {
  float az = fabsf(z);
  float e  = __expf(-2.0f * az);
  float r  = (1.0f - e) / (1.0f + e);
  return copysignf(r, z);
}
__device__ __forceinline__ unsigned tagmiss(u64 p0, u64 p1, u64 p2, unsigned tag) {
  unsigned m = (((unsigned)p0) & 15u) ^ tag;
  m |= (((unsigned)(p0 >> 32)) & 15u) ^ tag;
  m |= (((unsigned)p1) & 15u) ^ tag;
  m |= (((unsigned)(p1 >> 32)) & 15u) ^ tag;
  m |= (((unsigned)p2) & 15u) ^ tag;
  m |= (((unsigned)(p2 >> 32)) & 15u) ^ tag;
  return m;
}

// R5: LDS-resident weights, 13.2ms (~7750 cy/step) — serial poll/matvec/
// reduce/gates with 2 barriers. R6 restructure:
//  - wave u owns ALL 4 gates of unit u -> gates+publish in-wave, ONE barrier
//  - waves 6,7: dedicated poll (2 lines/lane); wave 6 also computes x-proj
//    (h-independent) pre-barrier
//  - waves 0-5 prefetch half their weight float4s into regs post-publish ->
//    LDS stream overlaps the inter-block handoff
//  - reduction: fold quarters (xor16/32) -> select -> 4-stage -> 15 DS ops
//    instead of 24
__global__
__attribute__((amdgpu_flat_work_group_size(NT, NT), amdgpu_waves_per_eu(2, 2)))
void lstm_fused(
    const float* __restrict__ x,    // (4096, 20)
    const float* __restrict__ Wih,  // (6000, 20)
    const float* __restrict__ Whh,  // (6000, 1500)
    const float* __restrict__ bih,  // (6000,)
    const float* __restrict__ bhh,  // (6000,)
    const float* __restrict__ W1,   // (1875, 1500)
    const float* __restrict__ b1,   // (1875,)
    const float* __restrict__ W2,   // (20, 1875)
    const float* __restrict__ b2,   // (20,)
    float* __restrict__ out,        // (20,)
    unsigned* __restrict__ ws)
{
  const int tid = threadIdx.x;
  const int bid = blockIdx.x;
  const int wv  = tid >> 6;   // wave 0..7
  const int ln  = tid & 63;

  unsigned* pub  = ws;          // [2][NB][8] dwords: 6 tagged h + pad (32B lines)
  unsigned* hidp = ws + 4096;   // [1875] tagged hid values

  // 24 rows x 384 float4; row r = u*4+g (u=unit, g=gate). 147,456 B
  __shared__ __align__(16) float lds_w[24 * 1536];
  __shared__ __align__(16) float lds_h[1536];   // h(t), zero-padded
  __shared__ float lds_xp[2][24];               // x-proj, double-buffered: [par][g*6+u]
  float* lds_hd = lds_w;                        // alias (block 0, post-loop only)

  if (tid < 36) lds_h[1500 + tid] = 0.0f;       // zero pad once

  // ---- stage W_hh slice into LDS ----
  {
    const float4* whh4 = (const float4*)Whh;
    float4* w4 = (float4*)lds_w;
    for (int idx = tid; idx < 24 * 384; idx += NT) {
      const int r = idx / 384, k4 = idx - r * 384;
      const int u = r >> 2, g = r & 3;
      const int grow = g * HH + bid * 6 + u;
      w4[idx] = (k4 < 375) ? whh4[(size_t)grow * 375 + k4]
                           : make_float4(0.f, 0.f, 0.f, 0.f);
    }
  }

  // matvec row bases (waves 0..5; harmless for others)
  const float4* h4 = (const float4*)lds_h;
  const int uu = (wv < 6) ? wv : 0;
  const float4* wr0 = (const float4*)lds_w + (size_t)(uu * 4 + 0) * 384;
  const float4* wr1 = (const float4*)lds_w + (size_t)(uu * 4 + 1) * 384;
  const float4* wr2 = (const float4*)lds_w + (size_t)(uu * 4 + 2) * 384;
  const float4* wr3 = (const float4*)lds_w + (size_t)(uu * 4 + 3) * 384;

  // ---- wave 6 lanes 0..23: persistent Wih row (gate g=ln/6, unit u=ln%6) ----
  float4 wx0, wx1, wx2, wx3, wx4;
  float bias = 0.f;
  if (wv == 6 && ln < 24) {
    const int g = ln / 6, u = ln - g * 6;
    const int row = g * HH + bid * 6 + u;
    const float4* s = (const float4*)(Wih + row * 20);
    wx0 = s[0]; wx1 = s[1]; wx2 = s[2]; wx3 = s[3]; wx4 = s[4];
    bias = bih[row] + bhh[row];
  }

  float c = 0.f;  // cell state: lane 0 of wave u holds c_u

  // init publish: h(0)=0 with tag 1 (tag(h(k)) = (k+1)&15)
  if (tid < 6) AST4(pub + (0 * NB + bid) * 8 + tid, 1u);

  __syncthreads();   // weights staged before first prefetch

  // initial weight prefetch (m = 0..2 of each gate row)
  float4 pw[12];
  if (wv < 6) {
    #pragma unroll
    for (int g = 0; g < 4; ++g) {
      const float4* wr = (g == 0) ? wr0 : (g == 1) ? wr1 : (g == 2) ? wr2 : wr3;
      #pragma unroll
      for (int m = 0; m < 3; ++m) pw[g * 3 + m] = wr[ln + 64 * m];
    }
  }

  for (int t = 0; t < TT; ++t) {
    const int s = t & 1;
    const unsigned tag = (unsigned)((t + 1) & 15);

    if (wv >= 6) {
      // ---- wave 6: x-projection for step t (h-independent) ----
      if (wv == 6 && ln < 24) {
        const float4* xx = (const float4*)(x + 20 * t);
        const float4 x0 = xx[0], x1 = xx[1], x2 = xx[2], x3 = xx[3], x4 = xx[4];
        float sx = bias;
        sx += wx0.x*x0.x + wx0.y*x0.y + wx0.z*x0.z + wx0.w*x0.w;
        sx += wx1.x*x1.x + wx1.y*x1.y + wx1.z*x1.z + wx1.w*x1.w;
        sx += wx2.x*x2.x + wx2.y*x2.y + wx2.z*x2.z + wx2.w*x2.w;
        sx += wx3.x*x3.x + wx3.y*x3.y + wx3.z*x3.z + wx3.w*x3.w;
        sx += wx4.x*x4.x + wx4.y*x4.y + wx4.z*x4.z + wx4.w*x4.w;
        lds_xp[s][ln] = sx;
      }
      // ---- poll h(t): lane pi handles lines pi and pi+128 ----
      const int pi = tid - 384;              // 0..127
      const bool two = (pi + 128) < NB;
      const u64* A = (const u64*)(pub + (s * NB + pi) * 8);
      const u64* B = (const u64*)(pub + (s * NB + pi + 128) * 8);
      u64 a0, a1, a2, b0 = 0, b1 = 0, b2 = 0;
      for (;;) {
        a0 = ALD8(A + 0); a1 = ALD8(A + 1); a2 = ALD8(A + 2);
        unsigned m = tagmiss(a0, a1, a2, tag);
        if (two) {
          b0 = ALD8(B + 0); b1 = ALD8(B + 1); b2 = ALD8(B + 2);
          m |= tagmiss(b0, b1, b2, tag);
        }
        if (!m) break;
        __builtin_amdgcn_s_sleep(1);
      }
      float2* d1 = (float2*)(lds_h + pi * 6);
      d1[0] = make_float2(__uint_as_float((unsigned)a0), __uint_as_float((unsigned)(a0 >> 32)));
      d1[1] = make_float2(__uint_as_float((unsigned)a1), __uint_as_float((unsigned)(a1 >> 32)));
      d1[2] = make_float2(__uint_as_float((unsigned)a2), __uint_as_float((unsigned)(a2 >> 32)));
      if (two) {
        float2* d2 = (float2*)(lds_h + (pi + 128) * 6);
        d2[0] = make_float2(__uint_as_float((unsigned)b0), __uint_as_float((unsigned)(b0 >> 32)));
        d2[1] = make_float2(__uint_as_float((unsigned)b1), __uint_as_float((unsigned)(b1 >> 32)));
        d2[2] = make_float2(__uint_as_float((unsigned)b2), __uint_as_float((unsigned)(b2 >> 32)));
      }
    }
    __syncthreads();   // the ONLY barrier per step

    if (wv < 6) {
      // ---- h fragments + fresh weight loads (m=3..5) ----
      float4 hv[6];
      #pragma unroll
      for (int m = 0; m < 6; ++m) hv[m] = h4[ln + 64 * m];
      float4 qw[12];
      #pragma unroll
      for (int g = 0; g < 4; ++g) {
        const float4* wr = (g == 0) ? wr0 : (g == 1) ? wr1 : (g == 2) ? wr2 : wr3;
        #pragma unroll
        for (int m = 0; m < 3; ++m) qw[g * 3 + m] = wr[ln + 64 * (m + 3)];
      }
      float a[4];
      #pragma unroll
      for (int g = 0; g < 4; ++g) {
        float sum = 0.f;
        #pragma unroll
        for (int m = 0; m < 3; ++m) {
          const float4 q = pw[g * 3 + m], hvv = hv[m];
          sum = fmaf(q.x, hvv.x, sum); sum = fmaf(q.y, hvv.y, sum);
          sum = fmaf(q.z, hvv.z, sum); sum = fmaf(q.w, hvv.w, sum);
        }
        #pragma unroll
        for (int m = 0; m < 3; ++m) {
          const float4 q = qw[g * 3 + m], hvv = hv[m + 3];
          sum = fmaf(q.x, hvv.x, sum); sum = fmaf(q.y, hvv.y, sum);
          sum = fmaf(q.z, hvv.z, sum); sum = fmaf(q.w, hvv.w, sum);
        }
        a[g] = sum;
      }
      // ---- reduce: fold quarters, select, 4-stage, gather (15 DS ops) ----
      #pragma unroll
      for (int g = 0; g < 4; ++g) {
        a[g] += __shfl_xor(a[g], 16, 64);
        a[g] += __shfl_xor(a[g], 32, 64);
      }
      const int q4 = ln >> 4;
      float v = (q4 == 0) ? a[0] : (q4 == 1) ? a[1] : (q4 == 2) ? a[2] : a[3];
      v += __shfl_xor(v, 1, 64);
      v += __shfl_xor(v, 2, 64);
      v += __shfl_xor(v, 4, 64);
      v += __shfl_xor(v, 8, 64);
      const float zfs = __shfl(v, 16, 64);
      const float zgs = __shfl(v, 32, 64);
      const float zos = __shfl(v, 48, 64);
      if (ln == 0) {
        const float zi = v   + lds_xp[s][0 + wv];
        const float zf = zfs + lds_xp[s][6 + wv];
        const float zg = zgs + lds_xp[s][12 + wv];
        const float zo = zos + lds_xp[s][18 + wv];
        const float ig = fast_sigmoid(zi);
        const float fg = fast_sigmoid(zf);
        const float gg = fast_tanh(zg);
        const float og = fast_sigmoid(zo);
        c = fg * c + ig * gg;
        const float hn = og * fast_tanh(c);
        const unsigned bits = (__float_as_uint(hn) & ~15u) | (unsigned)((t + 2) & 15);
        AST4(pub + (((t + 1) & 1) * NB + bid) * 8 + wv, bits);
      }
      // ---- prefetch weights for t+1 (overlaps next poll window) ----
      #pragma unroll
      for (int g = 0; g < 4; ++g) {
        const float4* wr = (g == 0) ? wr0 : (g == 1) ? wr1 : (g == 2) ? wr2 : wr3;
        #pragma unroll
        for (int m = 0; m < 3; ++m) pw[g * 3 + m] = wr[ln + 64 * m];
      }
    }
  }

  // ---- final gather h(TT): slot 0, tag (TT+1)&15 = 1 ----
  if (wv >= 6) {
    const unsigned tagf = (unsigned)((TT + 1) & 15);
    const int pi = tid - 384;
    const bool two = (pi + 128) < NB;
    const u64* A = (const u64*)(pub + (0 * NB + pi) * 8);
    const u64* B = (const u64*)(pub + (0 * NB + pi + 128) * 8);
    u64 a0, a1, a2, b0 = 0, b1 = 0, b2 = 0;
    for (;;) {
      a0 = ALD8(A + 0); a1 = ALD8(A + 1); a2 = ALD8(A + 2);
      unsigned m = tagmiss(a0, a1, a2, tagf);
      if (two) {
        b0 = ALD8(B + 0); b1 = ALD8(B + 1); b2 = ALD8(B + 2);
        m |= tagmiss(b0, b1, b2, tagf);
      }
      if (!m) break;
      __builtin_amdgcn_s_sleep(1);
    }
    float2* d1 = (float2*)(lds_h + pi * 6);
    d1[0] = make_float2(__uint_as_float((unsigned)a0), __uint_as_float((unsigned)(a0 >> 32)));
    d1[1] = make_float2(__uint_as_float((unsigned)a1), __uint_as_float((unsigned)(a1 >> 32)));
    d1[2] = make_float2(__uint_as_float((unsigned)a2), __uint_as_float((unsigned)(a2 >> 32)));
    if (two) {
      float2* d2 = (float2*)(lds_h + (pi + 128) * 6);
      d2[0] = make_float2(__uint_as_float((unsigned)b0), __uint_as_float((unsigned)(b0 >> 32)));
      d2[1] = make_float2(__uint_as_float((unsigned)b1), __uint_as_float((unsigned)(b1 >> 32)));
      d2[2] = make_float2(__uint_as_float((unsigned)b2), __uint_as_float((unsigned)(b2 >> 32)));
    }
  }
  __syncthreads();

  // ---- MLP layer 1: wave wv computes row r = bid + 250*wv ----
  {
    const int r = bid + 250 * wv;
    if (r < 1875) {
      const float4* wrow = (const float4*)(W1 + (size_t)r * HH);
      float ss = 0.f;
      #pragma unroll
      for (int m = 0; m < 6; ++m) {
        const int idx = ln + 64 * m;
        if (idx < 375) {
          const float4 a = wrow[idx], hvv = h4[idx];
          ss += a.x*hvv.x + a.y*hvv.y + a.z*hvv.z + a.w*hvv.w;
        }
      }
      #pragma unroll
      for (int off = 32; off > 0; off >>= 1) ss += __shfl_xor(ss, off, 64);
      if (ln == 0) {
        const float vv = ss + b1[r];
        AST4(hidp + r, (__float_as_uint(vv) & ~15u) | 5u);  // tag 5 (!= poison 10)
      }
    }
  }
  if (bid != 0) return;

  // ---- block 0: gather hid (into lds_w alias), MLP layer 2, write out ----
  __syncthreads();
  for (int j = tid; j < 1875; j += NT) {
    unsigned bts;
    for (;;) {
      bts = ALD4(hidp + j);
      if ((bts & 15u) == 5u) break;
      __builtin_amdgcn_s_sleep(1);
    }
    lds_hd[j] = __uint_as_float(bts);
  }
  __syncthreads();

  for (int r = wv; r < 20; r += 8) {
    float ss = 0.f;
    for (int k = ln; k < 1875; k += 64)
      ss = fmaf(W2[(size_t)r * 1875 + k], lds_hd[k], ss);
    #pragma unroll
    for (int off = 32; off > 0; off >>= 1) ss += __shfl_xor(ss, off, 64);
    if (ln == 0) out[r] = ss + b2[r];
  }
}

extern "C" void kernel_launch(void* const* d_in, const int* in_sizes, int n_in,
                              void* d_out, int out_size, void* d_ws, size_t ws_size,
                              hipStream_t stream) {
  const float* x   = (const float*)d_in[0];
  const float* Wih = (const float*)d_in[1];
  const float* Whh = (const float*)d_in[2];
  const float* bih = (const float*)d_in[3];
  const float* bhh = (const float*)d_in[4];
  const float* W1  = (const float*)d_in[5];
  const float* b1  = (const float*)d_in[6];
  const float* W2  = (const float*)d_in[7];
  const float* b2  = (const float*)d_in[8];
  float* out   = (float*)d_out;
  unsigned* ws = (unsigned*)d_ws;   // uses ~24 KB

  // 250 blocks x 512 threads, ~154 KB LDS -> exactly 1 block/CU, 250 <= 256
  // CUs: all blocks co-resident -> the tagged-line exchange cannot deadlock.
  hipLaunchKernelGGL(lstm_fused, dim3(NB), dim3(NT), 0, stream,
                     x, Wih, Whh, bih, bhh, W1, b1, W2, b2, out, ws);
}

// Round 7
// 12506.535 us; speedup vs baseline: 1.6928x; 1.6928x over previous
//
#include <hip/hip_runtime.h>
#include <math.h>

#define TT 4096
#define HH 1500
#define NB 250     // blocks; each owns 6 hidden units
#define NT 512     // 8 waves: 0..5 matvec (wave u = unit u, 4 gate-rows each),
                   //          6 = x-proj + poll, 7 = poll + gates + publish

typedef unsigned long long u64;

#define ALD8(p)   __hip_atomic_load((p), __ATOMIC_RELAXED, __HIP_MEMORY_SCOPE_AGENT)
#define ALD4(p)   __hip_atomic_load((p), __ATOMIC_RELAXED, __HIP_MEMORY_SCOPE_AGENT)
#define AST4(p,v) __hip_atomic_store((p), (v), __ATOMIC_RELAXED, __HIP_MEMORY_SCOPE_AGENT)

__device__ __forceinline__ float fast_sigmoid(float z) {
  return 1.0f / (1.0f + __expf(-z));
}
__device__ __forceinline__ float fast_tanh(float z) {
  float az = fabsf(z);
  float e  = __expf(-2.0f * az);
  float r  = (1.0f - e) / (1.0f + e);
  return copysignf(r, z);
}
__device__ __forceinline__ unsigned tagmiss(u64 p0, u64 p1, u64 p2, unsigned tag) {
  unsigned m = (((unsigned)p0) & 15u) ^ tag;
  m |= (((unsigned)(p0 >> 32)) & 15u) ^ tag;
  m |= (((unsigned)p1) & 15u) ^ tag;
  m |= (((unsigned)(p1 >> 32)) & 15u) ^ tag;
  m |= (((unsigned)p2) & 15u) ^ tag;
  m |= (((unsigned)(p2 >> 32)) & 15u) ^ tag;
  return m;
}

// R5 (13.2ms): serial poll->matvec->reduce->gates, 2 barriers.
// R6 (21.2ms REGRESSION): one barrier but publish fragmented across 6 waves
//   -> WRITE_SIZE 6x, staggered line validity, extra poll retries.
// R7: R6's overlap pipeline + R5's coalesced single-wave publish:
//   P: waves0-5 prefetch 12 w-float4 (hides under poll); wave6 xproj; 6+7 poll
//   A; M: waves0-5 h-read+FMA+fold-select-reduce -> lds_gs; wave6 x(t+1) pref
//   B; G: wave7 lanes0-5 gates (c resident) + ONE coalesced tagged publish.
__global__
__attribute__((amdgpu_flat_work_group_size(NT, NT), amdgpu_waves_per_eu(2, 2)))
void lstm_fused(
    const float* __restrict__ x,    // (4096, 20)
    const float* __restrict__ Wih,  // (6000, 20)
    const float* __restrict__ Whh,  // (6000, 1500)
    const float* __restrict__ bih,  // (6000,)
    const float* __restrict__ bhh,  // (6000,)
    const float* __restrict__ W1,   // (1875, 1500)
    const float* __restrict__ b1,   // (1875,)
    const float* __restrict__ W2,   // (20, 1875)
    const float* __restrict__ b2,   // (20,)
    float* __restrict__ out,        // (20,)
    unsigned* __restrict__ ws)
{
  const int tid = threadIdx.x;
  const int bid = blockIdx.x;
  const int wv  = tid >> 6;   // wave 0..7
  const int ln  = tid & 63;

  unsigned* pub  = ws;          // [2][NB][8] dwords: 6 tagged h + pad (32B lines)
  unsigned* hidp = ws + 4096;   // [1875] tagged hid values

  // 24 rows x 384 float4; row r = u*4+g (u=unit, g=gate). 147,456 B
  __shared__ __align__(16) float lds_w[24 * 1536];
  __shared__ __align__(16) float lds_h[1536];   // h(t), zero-padded
  __shared__ float lds_xp[2][24];               // x-proj, dbuf: [par][g*6+u]
  __shared__ float lds_gs[4][6];                // gate sums: [g][u]
  float* lds_hd = lds_w;                        // alias (block 0, post-loop only)

  if (tid < 36) lds_h[1500 + tid] = 0.0f;       // zero pad once

  // ---- stage W_hh slice into LDS ----
  {
    const float4* whh4 = (const float4*)Whh;
    float4* w4 = (float4*)lds_w;
    for (int idx = tid; idx < 24 * 384; idx += NT) {
      const int r = idx / 384, k4 = idx - r * 384;
      const int u = r >> 2, g = r & 3;
      const int grow = g * HH + bid * 6 + u;
      w4[idx] = (k4 < 375) ? whh4[(size_t)grow * 375 + k4]
                           : make_float4(0.f, 0.f, 0.f, 0.f);
    }
  }

  // matvec row bases (waves 0..5)
  const float4* h4 = (const float4*)lds_h;
  const int uu = (wv < 6) ? wv : 0;
  const float4* wr0 = (const float4*)lds_w + (size_t)(uu * 4 + 0) * 384;
  const float4* wr1 = (const float4*)lds_w + (size_t)(uu * 4 + 1) * 384;
  const float4* wr2 = (const float4*)lds_w + (size_t)(uu * 4 + 2) * 384;
  const float4* wr3 = (const float4*)lds_w + (size_t)(uu * 4 + 3) * 384;

  // ---- wave 6 lanes 0..23: persistent Wih row (g=ln/6, u=ln%6) + x(0) regs ----
  float4 wx0, wx1, wx2, wx3, wx4;
  float4 xr0, xr1, xr2, xr3, xr4;
  float bias = 0.f;
  if (wv == 6 && ln < 24) {
    const int g = ln / 6, u = ln - g * 6;
    const int row = g * HH + bid * 6 + u;
    const float4* s = (const float4*)(Wih + row * 20);
    wx0 = s[0]; wx1 = s[1]; wx2 = s[2]; wx3 = s[3]; wx4 = s[4];
    bias = bih[row] + bhh[row];
    const float4* xx = (const float4*)x;
    xr0 = xx[0]; xr1 = xx[1]; xr2 = xx[2]; xr3 = xx[3]; xr4 = xx[4];
  }

  float c = 0.f;  // cell state: wave 7 lanes 0..5 (unit = ln)

  // init publish: h(0)=0 with tag 1 (tag(h(k)) = (k+1)&15)
  if (tid < 6) AST4(pub + (0 * NB + bid) * 8 + tid, 1u);

  __syncthreads();   // weights staged

  for (int t = 0; t < TT; ++t) {
    const int s = t & 1;
    const unsigned tag = (unsigned)((t + 1) & 15);

    // ================= P phase (pre-A) =================
    float4 pw[12];
    if (wv < 6) {
      // prefetch first half of weights — overlaps the poll below
      #pragma unroll
      for (int g = 0; g < 4; ++g) {
        const float4* wr = (g == 0) ? wr0 : (g == 1) ? wr1 : (g == 2) ? wr2 : wr3;
        #pragma unroll
        for (int m = 0; m < 3; ++m) pw[g * 3 + m] = wr[ln + 64 * m];
      }
    } else {
      if (wv == 6 && ln < 24) {
        // x-projection for step t (from registers, h-independent)
        float sx = bias;
        sx += wx0.x*xr0.x + wx0.y*xr0.y + wx0.z*xr0.z + wx0.w*xr0.w;
        sx += wx1.x*xr1.x + wx1.y*xr1.y + wx1.z*xr1.z + wx1.w*xr1.w;
        sx += wx2.x*xr2.x + wx2.y*xr2.y + wx2.z*xr2.z + wx2.w*xr2.w;
        sx += wx3.x*xr3.x + wx3.y*xr3.y + wx3.z*xr3.z + wx3.w*xr3.w;
        sx += wx4.x*xr4.x + wx4.y*xr4.y + wx4.z*xr4.z + wx4.w*xr4.w;
        lds_xp[s][ln] = sx;
      }
      // poll h(t): lane pi handles lines pi and pi+128
      const int pi = tid - 384;              // 0..127
      const bool two = (pi + 128) < NB;
      const u64* A = (const u64*)(pub + (s * NB + pi) * 8);
      const u64* B = (const u64*)(pub + (s * NB + pi + 128) * 8);
      u64 a0, a1, a2, b0 = 0, b1 = 0, b2 = 0;
      for (;;) {
        a0 = ALD8(A + 0); a1 = ALD8(A + 1); a2 = ALD8(A + 2);
        unsigned m = tagmiss(a0, a1, a2, tag);
        if (two) {
          b0 = ALD8(B + 0); b1 = ALD8(B + 1); b2 = ALD8(B + 2);
          m |= tagmiss(b0, b1, b2, tag);
        }
        if (!m) break;
        __builtin_amdgcn_s_sleep(1);
      }
      float2* d1 = (float2*)(lds_h + pi * 6);
      d1[0] = make_float2(__uint_as_float((unsigned)a0), __uint_as_float((unsigned)(a0 >> 32)));
      d1[1] = make_float2(__uint_as_float((unsigned)a1), __uint_as_float((unsigned)(a1 >> 32)));
      d1[2] = make_float2(__uint_as_float((unsigned)a2), __uint_as_float((unsigned)(a2 >> 32)));
      if (two) {
        float2* d2 = (float2*)(lds_h + (pi + 128) * 6);
        d2[0] = make_float2(__uint_as_float((unsigned)b0), __uint_as_float((unsigned)(b0 >> 32)));
        d2[1] = make_float2(__uint_as_float((unsigned)b1), __uint_as_float((unsigned)(b1 >> 32)));
        d2[2] = make_float2(__uint_as_float((unsigned)b2), __uint_as_float((unsigned)(b2 >> 32)));
      }
    }
    __syncthreads();   // ---- A: h(t), xp(t) staged ----

    // ================= M phase =================
    if (wv < 6) {
      float4 hv[6];
      #pragma unroll
      for (int m = 0; m < 6; ++m) hv[m] = h4[ln + 64 * m];
      float4 qw[12];
      #pragma unroll
      for (int g = 0; g < 4; ++g) {
        const float4* wr = (g == 0) ? wr0 : (g == 1) ? wr1 : (g == 2) ? wr2 : wr3;
        #pragma unroll
        for (int m = 0; m < 3; ++m) qw[g * 3 + m] = wr[ln + 64 * (m + 3)];
      }
      float a[4];
      #pragma unroll
      for (int g = 0; g < 4; ++g) {
        float sum = 0.f;
        #pragma unroll
        for (int m = 0; m < 3; ++m) {
          const float4 q = pw[g * 3 + m], hvv = hv[m];
          sum = fmaf(q.x, hvv.x, sum); sum = fmaf(q.y, hvv.y, sum);
          sum = fmaf(q.z, hvv.z, sum); sum = fmaf(q.w, hvv.w, sum);
        }
        #pragma unroll
        for (int m = 0; m < 3; ++m) {
          const float4 q = qw[g * 3 + m], hvv = hv[m + 3];
          sum = fmaf(q.x, hvv.x, sum); sum = fmaf(q.y, hvv.y, sum);
          sum = fmaf(q.z, hvv.z, sum); sum = fmaf(q.w, hvv.w, sum);
        }
        a[g] = sum;
      }
      // fold-select reduce: 12 swizzles + 1 ds_write
      #pragma unroll
      for (int g = 0; g < 4; ++g) {
        a[g] += __shfl_xor(a[g], 16, 64);
        a[g] += __shfl_xor(a[g], 32, 64);
      }
      const int q4 = ln >> 4;
      float v = (q4 == 0) ? a[0] : (q4 == 1) ? a[1] : (q4 == 2) ? a[2] : a[3];
      v += __shfl_xor(v, 1, 64);
      v += __shfl_xor(v, 2, 64);
      v += __shfl_xor(v, 4, 64);
      v += __shfl_xor(v, 8, 64);
      if ((ln & 15) == 0) lds_gs[q4][wv] = v;
    } else if (wv == 6 && ln < 24 && (t + 1) < TT) {
      // prefetch x(t+1) while waves 0-5 compute
      const float4* xx = (const float4*)(x + 20 * (t + 1));
      xr0 = xx[0]; xr1 = xx[1]; xr2 = xx[2]; xr3 = xx[3]; xr4 = xx[4];
    }
    __syncthreads();   // ---- B: gate sums ready ----

    // ================= G phase: wave 7 only =================
    if (wv == 7 && ln < 6) {
      const int u = ln;
      const float zi = lds_gs[0][u] + lds_xp[s][0 + u];
      const float zf = lds_gs[1][u] + lds_xp[s][6 + u];
      const float zg = lds_gs[2][u] + lds_xp[s][12 + u];
      const float zo = lds_gs[3][u] + lds_xp[s][18 + u];
      const float ig = fast_sigmoid(zi);
      const float fg = fast_sigmoid(zf);
      const float gg = fast_tanh(zg);
      const float og = fast_sigmoid(zo);
      c = fg * c + ig * gg;
      const float hn = og * fast_tanh(c);
      const unsigned bits = (__float_as_uint(hn) & ~15u) | (unsigned)((t + 2) & 15);
      AST4(pub + (((t + 1) & 1) * NB + bid) * 8 + u, bits);  // ONE coalesced 24B
    }
  }

  // ---- final gather h(TT): slot 0, tag (TT+1)&15 = 1 ----
  if (wv >= 6) {
    const unsigned tagf = (unsigned)((TT + 1) & 15);
    const int pi = tid - 384;
    const bool two = (pi + 128) < NB;
    const u64* A = (const u64*)(pub + (0 * NB + pi) * 8);
    const u64* B = (const u64*)(pub + (0 * NB + pi + 128) * 8);
    u64 a0, a1, a2, b0 = 0, b1 = 0, b2 = 0;
    for (;;) {
      a0 = ALD8(A + 0); a1 = ALD8(A + 1); a2 = ALD8(A + 2);
      unsigned m = tagmiss(a0, a1, a2, tagf);
      if (two) {
        b0 = ALD8(B + 0); b1 = ALD8(B + 1); b2 = ALD8(B + 2);
        m |= tagmiss(b0, b1, b2, tagf);
      }
      if (!m) break;
      __builtin_amdgcn_s_sleep(1);
    }
    float2* d1 = (float2*)(lds_h + pi * 6);
    d1[0] = make_float2(__uint_as_float((unsigned)a0), __uint_as_float((unsigned)(a0 >> 32)));
    d1[1] = make_float2(__uint_as_float((unsigned)a1), __uint_as_float((unsigned)(a1 >> 32)));
    d1[2] = make_float2(__uint_as_float((unsigned)a2), __uint_as_float((unsigned)(a2 >> 32)));
    if (two) {
      float2* d2 = (float2*)(lds_h + (pi + 128) * 6);
      d2[0] = make_float2(__uint_as_float((unsigned)b0), __uint_as_float((unsigned)(b0 >> 32)));
      d2[1] = make_float2(__uint_as_float((unsigned)b1), __uint_as_float((unsigned)(b1 >> 32)));
      d2[2] = make_float2(__uint_as_float((unsigned)b2), __uint_as_float((unsigned)(b2 >> 32)));
    }
  }
  __syncthreads();

  // ---- MLP layer 1: wave wv computes row r = bid + 250*wv ----
  {
    const int r = bid + 250 * wv;
    if (r < 1875) {
      const float4* wrow = (const float4*)(W1 + (size_t)r * HH);
      float ss = 0.f;
      #pragma unroll
      for (int m = 0; m < 6; ++m) {
        const int idx = ln + 64 * m;
        if (idx < 375) {
          const float4 a = wrow[idx], hvv = h4[idx];
          ss += a.x*hvv.x + a.y*hvv.y + a.z*hvv.z + a.w*hvv.w;
        }
      }
      #pragma unroll
      for (int off = 32; off > 0; off >>= 1) ss += __shfl_xor(ss, off, 64);
      if (ln == 0) {
        const float vv = ss + b1[r];
        AST4(hidp + r, (__float_as_uint(vv) & ~15u) | 5u);  // tag 5 (!= poison 10)
      }
    }
  }
  if (bid != 0) return;

  // ---- block 0: gather hid (into lds_w alias), MLP layer 2, write out ----
  __syncthreads();
  for (int j = tid; j < 1875; j += NT) {
    unsigned bts;
    for (;;) {
      bts = ALD4(hidp + j);
      if ((bts & 15u) == 5u) break;
      __builtin_amdgcn_s_sleep(1);
    }
    lds_hd[j] = __uint_as_float(bts);
  }
  __syncthreads();

  for (int r = wv; r < 20; r += 8) {
    float ss = 0.f;
    for (int k = ln; k < 1875; k += 64)
      ss = fmaf(W2[(size_t)r * 1875 + k], lds_hd[k], ss);
    #pragma unroll
    for (int off = 32; off > 0; off >>= 1) ss += __shfl_xor(ss, off, 64);
    if (ln == 0) out[r] = ss + b2[r];
  }
}

extern "C" void kernel_launch(void* const* d_in, const int* in_sizes, int n_in,
                              void* d_out, int out_size, void* d_ws, size_t ws_size,
                              hipStream_t stream) {
  const float* x   = (const float*)d_in[0];
  const float* Wih = (const float*)d_in[1];
  const float* Whh = (const float*)d_in[2];
  const float* bih = (const float*)d_in[3];
  const float* bhh = (const float*)d_in[4];
  const float* W1  = (const float*)d_in[5];
  const float* b1  = (const float*)d_in[6];
  const float* W2  = (const float*)d_in[7];
  const float* b2  = (const float*)d_in[8];
  float* out   = (float*)d_out;
  unsigned* ws = (unsigned*)d_ws;   // uses ~24 KB

  // 250 blocks x 512 threads, ~154 KB LDS -> exactly 1 block/CU, 250 <= 256
  // CUs: all blocks co-resident -> the tagged-line exchange cannot deadlock.
  hipLaunchKernelGGL(lstm_fused, dim3(NB), dim3(NT), 0, stream,
                     x, Wih, Whh, bih, bhh, W1, b1, W2, b2, out, ws);
}